// Round 3
// baseline (1757.800 us; speedup 1.0000x reference)
//
#include <hip/hip_runtime.h>

// CALIBRATION PROBE (results bit-identical to reference kernel v1).
// Purpose: dur_us has been invariant (1307/1315/1315) across three very
// different schedules, and the splitter dispatch has never appeared in the
// rocprof top-5, so the kernel's true duration/BW is unobserved. This probe
// quadruples the HBM read traffic with zero-scaled FMAs (scale is a runtime
// kernel arg = 0.0f -> not foldable, loads not DCE-able) so that
//   dur_us - 1310  ==  3.22 GB / BW_achieved.
// Far reads are offset by {1024,2048,3072} segments AND {32,64,96} rows so
// every line's two uses are ~1 GB apart in the global access order ->
// no L2/L3 reuse, all compulsory HBM fetches.

#define SEG   128
#define LDIM  512
#define L4    (LDIM / 4)   // 128 float4 per L-row
#define NSEG  4096         // B*C*K total segments

__global__ __launch_bounds__(128) void splitter_probe(
    const float* __restrict__ x,
    const float* __restrict__ w,
    float* __restrict__ out,
    float zscale)                        // 0.0f at runtime
{
    const int bid = blockIdx.x;          // 0 .. 4095
    const int t   = threadIdx.x;         // 0 .. 127

    const float4* __restrict__ x4 = reinterpret_cast<const float4*>(x);

    const size_t base0 = (size_t)bid * (SEG * L4) + t;
    const size_t base1 = (size_t)((bid + 1024) & (NSEG - 1)) * (SEG * L4) + t;
    const size_t base2 = (size_t)((bid + 2048) & (NSEG - 1)) * (SEG * L4) + t;
    const size_t base3 = (size_t)((bid + 3072) & (NSEG - 1)) * (SEG * L4) + t;

    float4 acc = make_float4(0.f, 0.f, 0.f, 0.f);

#pragma unroll 4
    for (int s = 0; s < SEG; ++s) {
        const float ws = w[s];           // wave-uniform scalar load
        const float zs = ws * zscale;    // == 0.0f, unprovable at compile time

        const float4 v0 = x4[base0 + (size_t)s * L4];
        const float4 v1 = x4[base1 + (size_t)((s + 32) & (SEG - 1)) * L4];
        const float4 v2 = x4[base2 + (size_t)((s + 64) & (SEG - 1)) * L4];
        const float4 v3 = x4[base3 + (size_t)((s + 96) & (SEG - 1)) * L4];

        // real contribution
        acc.x = fmaf(v0.x, ws, acc.x);
        acc.y = fmaf(v0.y, ws, acc.y);
        acc.z = fmaf(v0.z, ws, acc.z);
        acc.w = fmaf(v0.w, ws, acc.w);
        // zero-scaled probe traffic (adds +/-0.0 exactly; x is finite)
        acc.x = fmaf(v1.x, zs, acc.x);
        acc.y = fmaf(v1.y, zs, acc.y);
        acc.z = fmaf(v1.z, zs, acc.z);
        acc.w = fmaf(v1.w, zs, acc.w);
        acc.x = fmaf(v2.x, zs, acc.x);
        acc.y = fmaf(v2.y, zs, acc.y);
        acc.z = fmaf(v2.z, zs, acc.z);
        acc.w = fmaf(v2.w, zs, acc.w);
        acc.x = fmaf(v3.x, zs, acc.x);
        acc.y = fmaf(v3.y, zs, acc.y);
        acc.z = fmaf(v3.z, zs, acc.z);
        acc.w = fmaf(v3.w, zs, acc.w);
    }

    reinterpret_cast<float4*>(out)[(size_t)bid * L4 + t] = acc;
}

extern "C" void kernel_launch(void* const* d_in, const int* in_sizes, int n_in,
                              void* d_out, int out_size, void* d_ws, size_t ws_size,
                              hipStream_t stream)
{
    const float* x = (const float*)d_in[0];   // [B,C,T,L] fp32
    const float* w = (const float*)d_in[1];   // [SEG] fp32
    float* out     = (float*)d_out;           // [B,C,K,L] fp32

    const int nblocks = out_size / LDIM;      // B*C*K = 4096
    splitter_probe<<<nblocks, 128, 0, stream>>>(x, w, out, 0.0f);
}

// Round 4
// 1316.799 us; speedup vs baseline: 1.3349x; 1.3349x over previous
//
#include <hip/hip_runtime.h>

// Problem: B=16, C=8, T=4096, L=512, K=32, SEG=128.
// out[b,c,k,l] = sum_s x[b,c,k*SEG+s,l] * w[s]
//
// v4: 4 independent read streams per wave. The calibration probe (round 3)
// delivered 6.05 TB/s to the CUs using 4 address streams/wave with 16 loads
// in flight, while the single-stream kernels v1-v3 all sit at 4.15 TB/s
// HBM read (kernel ~259 us, inferred via +451 us window shift with a 710 us
// probe dispatch). This version reproduces the probe's issue structure with
// ZERO redundant traffic: each wave walks rows {s, s+32, s+64, s+96} of its
// own segment concurrently (4 streams, 128 KB apart), 4 accumulators,
// unroll 4 -> 16 loads outstanding.

#define SEG  128
#define LDIM 512
#define L4   (LDIM / 4)   // 128 float4 per L-row

__global__ __launch_bounds__(128) void splitter_kernel(
    const float* __restrict__ x,
    const float* __restrict__ w,
    float* __restrict__ out)
{
    const int bid = blockIdx.x;       // 0 .. B*C*K-1 (4096)
    const int t   = threadIdx.x;      // 0 .. 127 : which float4 of the L row

    const float4* __restrict__ xb =
        reinterpret_cast<const float4*>(x) + (size_t)bid * (SEG * L4) + t;

    float4 a0 = make_float4(0.f, 0.f, 0.f, 0.f);
    float4 a1 = make_float4(0.f, 0.f, 0.f, 0.f);
    float4 a2 = make_float4(0.f, 0.f, 0.f, 0.f);
    float4 a3 = make_float4(0.f, 0.f, 0.f, 0.f);

#pragma unroll 4
    for (int s = 0; s < 32; ++s) {
        // wave-uniform weights -> scalar loads (constant-cached)
        const float w0 = w[s];
        const float w1 = w[s + 32];
        const float w2 = w[s + 64];
        const float w3 = w[s + 96];

        const float4 v0 = xb[(size_t)(s      ) * L4];
        const float4 v1 = xb[(size_t)(s + 32 ) * L4];
        const float4 v2 = xb[(size_t)(s + 64 ) * L4];
        const float4 v3 = xb[(size_t)(s + 96 ) * L4];

        a0.x = fmaf(v0.x, w0, a0.x); a0.y = fmaf(v0.y, w0, a0.y);
        a0.z = fmaf(v0.z, w0, a0.z); a0.w = fmaf(v0.w, w0, a0.w);

        a1.x = fmaf(v1.x, w1, a1.x); a1.y = fmaf(v1.y, w1, a1.y);
        a1.z = fmaf(v1.z, w1, a1.z); a1.w = fmaf(v1.w, w1, a1.w);

        a2.x = fmaf(v2.x, w2, a2.x); a2.y = fmaf(v2.y, w2, a2.y);
        a2.z = fmaf(v2.z, w2, a2.z); a2.w = fmaf(v2.w, w2, a2.w);

        a3.x = fmaf(v3.x, w3, a3.x); a3.y = fmaf(v3.y, w3, a3.y);
        a3.z = fmaf(v3.z, w3, a3.z); a3.w = fmaf(v3.w, w3, a3.w);
    }

    float4 acc;
    acc.x = (a0.x + a1.x) + (a2.x + a3.x);
    acc.y = (a0.y + a1.y) + (a2.y + a3.y);
    acc.z = (a0.z + a1.z) + (a2.z + a3.z);
    acc.w = (a0.w + a1.w) + (a2.w + a3.w);

    reinterpret_cast<float4*>(out)[(size_t)bid * L4 + t] = acc;
}

extern "C" void kernel_launch(void* const* d_in, const int* in_sizes, int n_in,
                              void* d_out, int out_size, void* d_ws, size_t ws_size,
                              hipStream_t stream)
{
    const float* x = (const float*)d_in[0];   // [B,C,T,L] fp32
    const float* w = (const float*)d_in[1];   // [SEG] fp32
    float* out     = (float*)d_out;           // [B,C,K,L] fp32

    const int nblocks = out_size / LDIM;      // B*C*K = 4096
    splitter_kernel<<<nblocks, 128, 0, stream>>>(x, w, out);
}